// Round 1
// baseline (1445.998 us; speedup 1.0000x reference)
//
#include <hip/hip_runtime.h>

typedef unsigned short u16;
typedef __attribute__((ext_vector_type(4))) float f4;
typedef __attribute__((ext_vector_type(8))) short s8v;    // 8 x bf16 MFMA frag (4 VGPRs)
typedef __attribute__((ext_vector_type(4))) unsigned short u16x4;

#define DEVINL __device__ __forceinline__

DEVINL float b2f(u16 u) { union { unsigned i; float f; } x; x.i = ((unsigned)u) << 16; return x.f; }
DEVINL u16 f2b(float f) {
  union { float f; unsigned i; } x; x.f = f;
  unsigned r = 0x7FFFu + ((x.i >> 16) & 1u);
  return (u16)((x.i + r) >> 16);
}

#define GLD_LDS16(g, l)                                                        \
  __builtin_amdgcn_global_load_lds((__attribute__((address_space(1))) void*)(g), \
                                   (__attribute__((address_space(3))) void*)(l), 16, 0, 0)

// ---------------- transpose + fp32->bf16 cast: out[C,R] = cast(in[R,C]^T) ----------------
__global__ __launch_bounds__(256) void k_transpose(const float* __restrict__ in,
                                                   u16* __restrict__ out, int R, int C) {
  __shared__ float t[32][33];
  int tx = threadIdx.x & 31, ty = threadIdx.x >> 5;
  int c0 = blockIdx.x * 32, r0 = blockIdx.y * 32;
#pragma unroll
  for (int i = 0; i < 32; i += 8)
    t[ty + i][tx] = in[(long)(r0 + ty + i) * C + (c0 + tx)];
  __syncthreads();
#pragma unroll
  for (int i = 0; i < 32; i += 8)
    out[(long)(c0 + ty + i) * R + (r0 + tx)] = f2b(t[tx][ty + i]);
}

// ---------------- LayerNorm over E=1024, one row per block, bf16 out ----------------
__global__ __launch_bounds__(256) void k_layernorm(const float* __restrict__ x,
                                                   const float* __restrict__ g,
                                                   const float* __restrict__ be,
                                                   u16* __restrict__ out) {
  long row = blockIdx.x;
  int tid = threadIdx.x;
  f4 v = ((const f4*)(x + row * 1024))[tid];
  float s = v[0] + v[1] + v[2] + v[3];
  float s2 = v[0] * v[0] + v[1] * v[1] + v[2] * v[2] + v[3] * v[3];
#pragma unroll
  for (int off = 32; off > 0; off >>= 1) {
    s += __shfl_down(s, off, 64);
    s2 += __shfl_down(s2, off, 64);
  }
  __shared__ float red[8];
  int wv = tid >> 6, ln = tid & 63;
  if (ln == 0) { red[wv] = s; red[4 + wv] = s2; }
  __syncthreads();
  s = red[0] + red[1] + red[2] + red[3];
  s2 = red[4] + red[5] + red[6] + red[7];
  float mean = s * (1.0f / 1024.0f);
  float var = s2 * (1.0f / 1024.0f) - mean * mean;
  float rs = rsqrtf(var + 1e-5f);
  f4 gg = ((const f4*)g)[tid];
  f4 bb = ((const f4*)be)[tid];
  u16x4 o;
#pragma unroll
  for (int i = 0; i < 4; ++i) o[i] = f2b((v[i] - mean) * rs * gg[i] + bb[i]);
  ((u16x4*)(out + row * 1024))[tid] = o;
}

// ---------------- QKV: [131072,64] @ [64,64] x3, MFMA 16x16x32 bf16 ----------------
// nx viewed as [B*S*H, 64] row-major == [B,S,H,D]; weights pre-transposed to [N=64,K=64].
__global__ __launch_bounds__(256) void k_qkv(const u16* __restrict__ nx, const u16* __restrict__ WqT,
                                             const u16* __restrict__ WkT, const u16* __restrict__ WvT,
                                             u16* __restrict__ q, u16* __restrict__ k,
                                             u16* __restrict__ v) {
  int tid = threadIdx.x, lane = tid & 63, wave = tid >> 6;
  int quad = lane >> 4, l16 = lane & 15;
  long rbase = (long)blockIdx.x * 64 + wave * 16;
  // A-frag: A[m=lane&15][k=quad*8+j], rows contiguous along K=64
  s8v a0 = *(const s8v*)(nx + (rbase + l16) * 64 + quad * 8);
  s8v a1 = *(const s8v*)(nx + (rbase + l16) * 64 + 32 + quad * 8);
  const u16* Ws[3] = {WqT, WkT, WvT};
  u16* Os[3] = {q, k, v};
#pragma unroll
  for (int t = 0; t < 3; ++t) {
#pragma unroll
    for (int j = 0; j < 4; ++j) {
      s8v b0 = *(const s8v*)(Ws[t] + (j * 16 + l16) * 64 + quad * 8);
      s8v b1 = *(const s8v*)(Ws[t] + (j * 16 + l16) * 64 + 32 + quad * 8);
      f4 acc = {0.f, 0.f, 0.f, 0.f};
      acc = __builtin_amdgcn_mfma_f32_16x16x32_bf16(a0, b0, acc, 0, 0, 0);
      acc = __builtin_amdgcn_mfma_f32_16x16x32_bf16(a1, b1, acc, 0, 0, 0);
#pragma unroll
      for (int r = 0; r < 4; ++r)  // C/D: col=lane&15, row=quad*4+r
        Os[t][(rbase + quad * 4 + r) * 64 + j * 16 + l16] = f2b(acc[r]);
    }
  }
}

// ---------------- causal flash attention, fp32 VALU, thread-per-query-row ----------------
// q,k,v,o layout: [B,S,H,D] bf16. scale = 1/sqrt(E) = 1/32 (reference scales by sqrt(embed)!).
__global__ __launch_bounds__(256) void k_attn(const u16* __restrict__ q, const u16* __restrict__ kk_,
                                              const u16* __restrict__ vv_, u16* __restrict__ o) {
  __shared__ float Ks[64 * 68];  // stride 68 floats: pad keeps 16B alignment, kills staging conflicts
  __shared__ float Vs[64 * 68];
  int tid = threadIdx.x;
  int bh = blockIdx.x, b = bh >> 4, h = bh & 15;
  int qg = blockIdx.y * 256 + tid;
  const u16* qp = q + (((long)(b * 1024 + qg) * 16 + h) << 6);
  f4 qv[16], Ov[16];
#pragma unroll
  for (int u = 0; u < 16; ++u) {
    u16x4 t = ((const u16x4*)qp)[u];
    qv[u] = f4{b2f(t[0]), b2f(t[1]), b2f(t[2]), b2f(t[3])};
    Ov[u] = f4{0.f, 0.f, 0.f, 0.f};
  }
  float m = -__builtin_inff(), l = 0.f;
  int ntiles = blockIdx.y * 4 + 4;
  for (int kt = 0; kt < ntiles; ++kt) {
    {  // stage 64 keys of K and V
      int key = tid >> 2;
      int dc = (tid & 3) * 16;
      long src = ((long)(b * 1024 + kt * 64 + key) * 16 + h) << 6;
      const u16x4* kp = (const u16x4*)(kk_ + src + dc);
      const u16x4* vp = (const u16x4*)(vv_ + src + dc);
      float* kd = Ks + key * 68 + dc;
      float* vd = Vs + key * 68 + dc;
#pragma unroll
      for (int u2 = 0; u2 < 4; ++u2) {
        u16x4 a = kp[u2], c = vp[u2];
#pragma unroll
        for (int e = 0; e < 4; ++e) {
          kd[u2 * 4 + e] = b2f(a[e]);
          vd[u2 * 4 + e] = b2f(c[e]);
        }
      }
    }
    __syncthreads();
    int kloc = qg - kt * 64;
    if (kloc >= 0) {
      int kmaxl = kloc < 63 ? kloc : 63;
      const f4* K4 = (const f4*)Ks;
      const f4* V4 = (const f4*)Vs;
      for (int kk = 0; kk <= kmaxl; kk += 8) {
        float s8[8];
        float cmax = -__builtin_inff();
#pragma unroll
        for (int c = 0; c < 8; ++c) {
          int key = kk + c;
          const f4* kr = K4 + key * 17;
          f4 a = {0.f, 0.f, 0.f, 0.f};
#pragma unroll
          for (int u = 0; u < 16; ++u) a += qv[u] * kr[u];  // broadcast LDS reads
          float sc = (a[0] + a[1] + a[2] + a[3]) * 0.03125f;
          s8[c] = (key <= kloc) ? sc : -__builtin_inff();
          cmax = fmaxf(cmax, s8[c]);
        }
        float mn = fmaxf(m, cmax);            // finite: key kk is always unmasked
        float alpha = __expf(m - mn);         // first chunk: exp(-inf)=0
        l *= alpha;
#pragma unroll
        for (int u = 0; u < 16; ++u) Ov[u] *= alpha;
#pragma unroll
        for (int c = 0; c < 8; ++c) {
          float p = __expf(s8[c] - mn);       // masked keys -> exp(-inf)=0
          l += p;
          const f4* vr = V4 + (kk + c) * 17;
#pragma unroll
          for (int u = 0; u < 16; ++u) Ov[u] += p * vr[u];
        }
        m = mn;
      }
    }
    __syncthreads();
  }
  float inv = 1.0f / l;  // diagonal key always present -> l >= ~1
  u16* op = o + (((long)(b * 1024 + qg) * 16 + h) << 6);
#pragma unroll
  for (int u = 0; u < 16; ++u) {
    u16x4 t;
#pragma unroll
    for (int e = 0; e < 4; ++e) t[e] = f2b(Ov[u][e] * inv);
    ((u16x4*)op)[u] = t;
  }
}

// ---------------- m97-style 128x128 GEMM, A[M,K] bf16, BT[N,K] bf16, fp32 acc ----------------
// EPI=1: out = bf16(relu(acc+bias));  EPI=2: out = fp32(resid + acc + bias)
template <int EPI>
__global__ __launch_bounds__(256) void k_gemm_bt(const u16* __restrict__ A, const u16* __restrict__ BT,
                                                 const float* __restrict__ bias,
                                                 const float* __restrict__ resid,
                                                 void* __restrict__ outp, int M, int N, int K) {
  __shared__ u16 sA[128 * 32];  // unpadded: global_load_lds needs lane-linear dest
  __shared__ u16 sB[128 * 32];
  int tid = threadIdx.x, lane = tid & 63, wave = tid >> 6;
  int quad = lane >> 4, l16 = lane & 15;
  int wm = wave >> 1, wn = wave & 1;
  long bm = blockIdx.x, bn = blockIdx.y;
  int srow = tid >> 2, scol = (tid & 3) * 8;  // LDS dest byte off = tid*16 = wavebase + lane*16
  const u16* ga = A + (bm * 128 + srow) * (long)K + scol;
  const u16* gb = BT + (bn * 128 + srow) * (long)K + scol;
  char* lA = (char*)sA + wave * 1024;  // wave-uniform LDS base
  char* lB = (char*)sB + wave * 1024;

  f4 acc[4][4];
#pragma unroll
  for (int i = 0; i < 4; ++i)
#pragma unroll
    for (int j = 0; j < 4; ++j) acc[i][j] = f4{0.f, 0.f, 0.f, 0.f};

  for (int k0 = 0; k0 < K; k0 += 32) {
    if (k0) __syncthreads();
    GLD_LDS16(ga + k0, lA);
    GLD_LDS16(ga + 64 * (long)K + k0, lA + 4096);
    GLD_LDS16(gb + k0, lB);
    GLD_LDS16(gb + 64 * (long)K + k0, lB + 4096);
    __syncthreads();  // compiler drains vmcnt(0) before s_barrier
    s8v aF[4], bF[4];
#pragma unroll
    for (int i = 0; i < 4; ++i)
      aF[i] = *(const s8v*)(sA + (wm * 64 + i * 16 + l16) * 32 + quad * 8);
#pragma unroll
    for (int j = 0; j < 4; ++j)
      bF[j] = *(const s8v*)(sB + (wn * 64 + j * 16 + l16) * 32 + quad * 8);
#pragma unroll
    for (int i = 0; i < 4; ++i)
#pragma unroll
      for (int j = 0; j < 4; ++j)
        acc[i][j] = __builtin_amdgcn_mfma_f32_16x16x32_bf16(aF[i], bF[j], acc[i][j], 0, 0, 0);
  }

#pragma unroll
  for (int i = 0; i < 4; ++i) {
#pragma unroll
    for (int j = 0; j < 4; ++j) {
      long row = bm * 128 + wm * 64 + i * 16 + quad * 4;
      int col = (int)bn * 128 + wn * 64 + j * 16 + l16;
      float bcol = bias[col];
#pragma unroll
      for (int r = 0; r < 4; ++r) {
        float val = acc[i][j][r] + bcol;
        if (EPI == 1) {
          ((u16*)outp)[(row + r) * (long)N + col] = f2b(val > 0.f ? val : 0.f);
        } else {
          ((float*)outp)[(row + r) * (long)N + col] = resid[(row + r) * (long)N + col] + val;
        }
      }
    }
  }
}

extern "C" void kernel_launch(void* const* d_in, const int* in_sizes, int n_in, void* d_out,
                              int out_size, void* d_ws, size_t ws_size, hipStream_t stream) {
  const float* x = (const float*)d_in[0];
  const float* Wq = (const float*)d_in[1];
  const float* Wk = (const float*)d_in[2];
  const float* Wv = (const float*)d_in[3];
  const float* Wo = (const float*)d_in[4];
  const float* bo = (const float*)d_in[5];
  const float* W1 = (const float*)d_in[6];
  const float* b1 = (const float*)d_in[7];
  const float* W2 = (const float*)d_in[8];
  const float* b2 = (const float*)d_in[9];
  const float* g1 = (const float*)d_in[10];
  const float* be1 = (const float*)d_in[11];
  const float* g2 = (const float*)d_in[12];
  const float* be2 = (const float*)d_in[13];

  char* ws = (char*)d_ws;
  const size_t MB = 1ull << 20;
  // ~179 MB of workspace, with lifetime-based aliasing:
  u16* nx = (u16*)(ws + 0);          // 16 MB  LN1 out; dead after QKV -> reused as attn out
  u16* qb = (u16*)(ws + 16 * MB);    // 16 MB  q; dead after attn -> reused as nx2
  u16* kb = (u16*)(ws + 32 * MB);    // 16 MB
  u16* vb = (u16*)(ws + 48 * MB);    // 16 MB
  float* x1 = (float*)(ws + 64 * MB);  // 32 MB  attn-sublayer output (fp32 residual trunk)
  u16* h1 = (u16*)(ws + 96 * MB);    // 64 MB  MLP hidden
  u16* WoT = (u16*)(ws + 160 * MB);  // 2 MB
  u16* W1T = (u16*)(ws + 162 * MB);  // 8 MB
  u16* W2T = (u16*)(ws + 170 * MB);  // 8 MB
  u16* WqT = (u16*)(ws + 178 * MB);  // 8 KB x3
  u16* WkT = WqT + 64 * 64;
  u16* WvT = WkT + 64 * 64;
  u16* ob = nx;
  u16* nx2 = qb;

  // weights -> bf16 [N,K]
  k_transpose<<<dim3(32, 32), 256, 0, stream>>>(Wo, WoT, 1024, 1024);
  k_transpose<<<dim3(128, 32), 256, 0, stream>>>(W1, W1T, 1024, 4096);
  k_transpose<<<dim3(32, 128), 256, 0, stream>>>(W2, W2T, 4096, 1024);
  k_transpose<<<dim3(2, 2), 256, 0, stream>>>(Wq, WqT, 64, 64);
  k_transpose<<<dim3(2, 2), 256, 0, stream>>>(Wk, WkT, 64, 64);
  k_transpose<<<dim3(2, 2), 256, 0, stream>>>(Wv, WvT, 64, 64);

  // attention sublayer
  k_layernorm<<<8192, 256, 0, stream>>>(x, g1, be1, nx);
  k_qkv<<<2048, 256, 0, stream>>>(nx, WqT, WkT, WvT, qb, kb, vb);
  k_attn<<<dim3(128, 4), 256, 0, stream>>>(qb, kb, vb, ob);
  k_gemm_bt<2><<<dim3(64, 8), 256, 0, stream>>>(ob, WoT, bo, x, x1, 8192, 1024, 1024);

  // MLP sublayer
  k_layernorm<<<8192, 256, 0, stream>>>(x1, g2, be2, nx2);
  k_gemm_bt<1><<<dim3(64, 32), 256, 0, stream>>>(nx2, W1T, b1, nullptr, h1, 8192, 4096, 1024);
  k_gemm_bt<2><<<dim3(64, 8), 256, 0, stream>>>(h1, W2T, b2, x1, d_out, 8192, 1024, 4096);
}

// Round 2
// 489.621 us; speedup vs baseline: 2.9533x; 2.9533x over previous
//
#include <hip/hip_runtime.h>

typedef unsigned short u16;
typedef __attribute__((ext_vector_type(4))) float f4;
typedef __attribute__((ext_vector_type(8))) short s8v;    // 8 x bf16 MFMA frag (4 VGPRs)
typedef __attribute__((ext_vector_type(4))) unsigned short u16x4;

#define DEVINL __device__ __forceinline__

DEVINL float b2f(u16 u) { union { unsigned i; float f; } x; x.i = ((unsigned)u) << 16; return x.f; }
DEVINL u16 f2b(float f) {
  union { float f; unsigned i; } x; x.f = f;
  unsigned r = 0x7FFFu + ((x.i >> 16) & 1u);
  return (u16)((x.i + r) >> 16);
}

#define GLD_LDS16(g, l)                                                        \
  __builtin_amdgcn_global_load_lds((__attribute__((address_space(1))) void*)(g), \
                                   (__attribute__((address_space(3))) void*)(l), 16, 0, 0)

// ---------------- transpose + fp32->bf16 cast: out[C,R] = cast(in[R,C]^T) ----------------
__global__ __launch_bounds__(256) void k_transpose(const float* __restrict__ in,
                                                   u16* __restrict__ out, int R, int C) {
  __shared__ float t[32][33];
  int tx = threadIdx.x & 31, ty = threadIdx.x >> 5;
  int c0 = blockIdx.x * 32, r0 = blockIdx.y * 32;
#pragma unroll
  for (int i = 0; i < 32; i += 8)
    t[ty + i][tx] = in[(long)(r0 + ty + i) * C + (c0 + tx)];
  __syncthreads();
#pragma unroll
  for (int i = 0; i < 32; i += 8)
    out[(long)(c0 + ty + i) * R + (r0 + tx)] = f2b(t[tx][ty + i]);
}

// ---------------- LayerNorm over E=1024, one row per block, bf16 out ----------------
__global__ __launch_bounds__(256) void k_layernorm(const float* __restrict__ x,
                                                   const float* __restrict__ g,
                                                   const float* __restrict__ be,
                                                   u16* __restrict__ out) {
  long row = blockIdx.x;
  int tid = threadIdx.x;
  f4 v = ((const f4*)(x + row * 1024))[tid];
  float s = v[0] + v[1] + v[2] + v[3];
  float s2 = v[0] * v[0] + v[1] * v[1] + v[2] * v[2] + v[3] * v[3];
#pragma unroll
  for (int off = 32; off > 0; off >>= 1) {
    s += __shfl_down(s, off, 64);
    s2 += __shfl_down(s2, off, 64);
  }
  __shared__ float red[8];
  int wv = tid >> 6, ln = tid & 63;
  if (ln == 0) { red[wv] = s; red[4 + wv] = s2; }
  __syncthreads();
  s = red[0] + red[1] + red[2] + red[3];
  s2 = red[4] + red[5] + red[6] + red[7];
  float mean = s * (1.0f / 1024.0f);
  float var = s2 * (1.0f / 1024.0f) - mean * mean;
  float rs = rsqrtf(var + 1e-5f);
  f4 gg = ((const f4*)g)[tid];
  f4 bb = ((const f4*)be)[tid];
  u16x4 o;
#pragma unroll
  for (int i = 0; i < 4; ++i) o[i] = f2b((v[i] - mean) * rs * gg[i] + bb[i]);
  ((u16x4*)(out + row * 1024))[tid] = o;
}

// ---------------- QKV: [131072,64] @ [64,64] x3, MFMA 16x16x32 bf16 ----------------
__global__ __launch_bounds__(256) void k_qkv(const u16* __restrict__ nx, const u16* __restrict__ WqT,
                                             const u16* __restrict__ WkT, const u16* __restrict__ WvT,
                                             u16* __restrict__ q, u16* __restrict__ k,
                                             u16* __restrict__ v) {
  int tid = threadIdx.x, lane = tid & 63, wave = tid >> 6;
  int quad = lane >> 4, l16 = lane & 15;
  long rbase = (long)blockIdx.x * 64 + wave * 16;
  s8v a0 = *(const s8v*)(nx + (rbase + l16) * 64 + quad * 8);
  s8v a1 = *(const s8v*)(nx + (rbase + l16) * 64 + 32 + quad * 8);
  const u16* Ws[3] = {WqT, WkT, WvT};
  u16* Os[3] = {q, k, v};
#pragma unroll
  for (int t = 0; t < 3; ++t) {
#pragma unroll
    for (int j = 0; j < 4; ++j) {
      s8v b0 = *(const s8v*)(Ws[t] + (j * 16 + l16) * 64 + quad * 8);
      s8v b1 = *(const s8v*)(Ws[t] + (j * 16 + l16) * 64 + 32 + quad * 8);
      f4 acc = {0.f, 0.f, 0.f, 0.f};
      acc = __builtin_amdgcn_mfma_f32_16x16x32_bf16(a0, b0, acc, 0, 0, 0);
      acc = __builtin_amdgcn_mfma_f32_16x16x32_bf16(a1, b1, acc, 0, 0, 0);
#pragma unroll
      for (int r = 0; r < 4; ++r)
        Os[t][(rbase + quad * 4 + r) * 64 + j * 16 + l16] = f2b(acc[r]);
    }
  }
}

// ---------------- MFMA flash attention (causal) ----------------
// q,k,v,o: [B,S,H,D] bf16. Block = 4 waves; each wave owns 16 queries of a
// 64-query tile. Per 64-key tile: S = Q K^T (MFMA, C-layout) -> online softmax
// (row stats per lane, shfl-xor over the 16-lane col group) -> P via LDS
// round-trip (C-layout -> A-layout, verified m120 pattern) -> O += P V (MFMA
// vs transposed-V B-frags). scale = 1/sqrt(E) = 1/32 per the reference.
__global__ __launch_bounds__(256) void k_attn_mfma(const u16* __restrict__ q,
                                                   const u16* __restrict__ kk,
                                                   const u16* __restrict__ vv,
                                                   u16* __restrict__ o) {
  constexpr int LDK = 72;  // row stride (u16): 144 B = 9*16 -> b128-aligned rows, non-pow2 banks
  __shared__ u16 Ks[64 * LDK];      // [key][d]
  __shared__ u16 Vt[64 * LDK];      // [d][key]
  __shared__ u16 Ps[4][16 * LDK];   // per-wave P [qrow][key]
  int tid = threadIdx.x, lane = tid & 63, wave = tid >> 6;
  int quad = lane >> 4, l16 = lane & 15;
  int b = blockIdx.x >> 4, h = blockIdx.x & 15;
  int qi = (int)gridDim.y - 1 - (int)blockIdx.y;  // heavy q-tiles dispatch first
  int q0 = qi * 64 + wave * 16;

  const u16* qp = q + (((long)(b * 1024 + q0 + l16)) * 16 + h) * 64;
  s8v aq0 = *(const s8v*)(qp + quad * 8);        // A-frag m=l16, k=quad*8+j
  s8v aq1 = *(const s8v*)(qp + 32 + quad * 8);

  f4 O[4];
  float m_[4], l_[4];
#pragma unroll
  for (int jd = 0; jd < 4; ++jd) O[jd] = f4{0.f, 0.f, 0.f, 0.f};
#pragma unroll
  for (int r = 0; r < 4; ++r) { m_[r] = -__builtin_inff(); l_[r] = 0.f; }

  for (int kt = 0; kt <= qi; ++kt) {
    __syncthreads();  // protect Ks/Vt reuse across tiles
    // ---- stage K [key][d] (b128) and V^T [d][key] (u16 scatter) ----
#pragma unroll
    for (int p = 0; p < 2; ++p) {
      int idx = p * 256 + tid;
      int row = idx >> 3, c8 = (idx & 7) * 8;
      long src = (((long)(b * 1024 + kt * 64 + row)) * 16 + h) * 64 + c8;
      *(s8v*)(Ks + row * LDK + c8) = *(const s8v*)(kk + src);
      s8v v8 = *(const s8v*)(vv + src);
#pragma unroll
      for (int e = 0; e < 8; ++e) Vt[(c8 + e) * LDK + row] = (u16)v8[e];
    }
    __syncthreads();

    // ---- S = Q K^T ----
    f4 sf[4];
#pragma unroll
    for (int jn = 0; jn < 4; ++jn) {
      s8v b0 = *(const s8v*)(Ks + (jn * 16 + l16) * LDK + quad * 8);
      s8v b1 = *(const s8v*)(Ks + (jn * 16 + l16) * LDK + 32 + quad * 8);
      f4 acc = f4{0.f, 0.f, 0.f, 0.f};
      acc = __builtin_amdgcn_mfma_f32_16x16x32_bf16(aq0, b0, acc, 0, 0, 0);
      acc = __builtin_amdgcn_mfma_f32_16x16x32_bf16(aq1, b1, acc, 0, 0, 0);
      sf[jn] = acc;
    }
    // ---- scale + causal mask + row max ----
    bool diag = (kt == qi);
    float rm[4];
#pragma unroll
    for (int r = 0; r < 4; ++r) rm[r] = -__builtin_inff();
#pragma unroll
    for (int jn = 0; jn < 4; ++jn)
#pragma unroll
      for (int r = 0; r < 4; ++r) {
        float v = sf[jn][r] * 0.03125f;
        if (diag && (jn * 16 + l16 > wave * 16 + quad * 4 + r)) v = -__builtin_inff();
        sf[jn][r] = v;
        rm[r] = fmaxf(rm[r], v);
      }
#pragma unroll
    for (int off = 1; off < 16; off <<= 1)
#pragma unroll
      for (int r = 0; r < 4; ++r) rm[r] = fmaxf(rm[r], __shfl_xor(rm[r], off, 64));
    // ---- online-softmax update ----
    float alpha[4], rs[4];
#pragma unroll
    for (int r = 0; r < 4; ++r) {
      float mn = fmaxf(m_[r], rm[r]);   // finite: key 0 of tile 0 / diagonal always unmasked
      alpha[r] = __expf(m_[r] - mn);    // first tile: exp(-inf) = 0
      m_[r] = mn;
      rs[r] = 0.f;
    }
#pragma unroll
    for (int jn = 0; jn < 4; ++jn)
#pragma unroll
      for (int r = 0; r < 4; ++r) {
        float p = __expf(sf[jn][r] - m_[r]);  // masked -> 0
        rs[r] += p;
        Ps[wave][(quad * 4 + r) * LDK + jn * 16 + l16] = f2b(p);
      }
#pragma unroll
    for (int off = 1; off < 16; off <<= 1)
#pragma unroll
      for (int r = 0; r < 4; ++r) rs[r] += __shfl_xor(rs[r], off, 64);
#pragma unroll
    for (int r = 0; r < 4; ++r) l_[r] = l_[r] * alpha[r] + rs[r];
#pragma unroll
    for (int jd = 0; jd < 4; ++jd)
#pragma unroll
      for (int r = 0; r < 4; ++r) O[jd][r] *= alpha[r];
    // wave-local RAW on Ps (per-wave buffer): drain DS queue, no barrier needed
    asm volatile("s_waitcnt lgkmcnt(0)" ::: "memory");
    // ---- O += P V ----
    s8v p0 = *(const s8v*)(&Ps[wave][l16 * LDK + quad * 8]);
    s8v p1 = *(const s8v*)(&Ps[wave][l16 * LDK + 32 + quad * 8]);
#pragma unroll
    for (int jd = 0; jd < 4; ++jd) {
      s8v b0 = *(const s8v*)(Vt + (jd * 16 + l16) * LDK + quad * 8);
      s8v b1 = *(const s8v*)(Vt + (jd * 16 + l16) * LDK + 32 + quad * 8);
      O[jd] = __builtin_amdgcn_mfma_f32_16x16x32_bf16(p0, b0, O[jd], 0, 0, 0);
      O[jd] = __builtin_amdgcn_mfma_f32_16x16x32_bf16(p1, b1, O[jd], 0, 0, 0);
    }
  }
  // ---- epilogue: O /= l, write [B,S,H,D] ----
#pragma unroll
  for (int r = 0; r < 4; ++r) {
    float inv = 1.0f / l_[r];
    u16* op = o + (((long)(b * 1024 + q0 + quad * 4 + r)) * 16 + h) * 64;
#pragma unroll
    for (int jd = 0; jd < 4; ++jd) op[jd * 16 + l16] = f2b(O[jd][r] * inv);
  }
}

// ---------------- m97-style 128x128 GEMM, A[M,K] bf16, BT[N,K] bf16, fp32 acc ----------------
// EPI=1: out = bf16(relu(acc+bias));  EPI=2: out = fp32(resid + acc + bias)
template <int EPI>
__global__ __launch_bounds__(256) void k_gemm_bt(const u16* __restrict__ A, const u16* __restrict__ BT,
                                                 const float* __restrict__ bias,
                                                 const float* __restrict__ resid,
                                                 void* __restrict__ outp, int M, int N, int K) {
  __shared__ u16 sA[128 * 32];  // unpadded: global_load_lds needs lane-linear dest
  __shared__ u16 sB[128 * 32];
  int tid = threadIdx.x, lane = tid & 63, wave = tid >> 6;
  int quad = lane >> 4, l16 = lane & 15;
  int wm = wave >> 1, wn = wave & 1;
  long bm = blockIdx.x, bn = blockIdx.y;
  int srow = tid >> 2, scol = (tid & 3) * 8;
  const u16* ga = A + (bm * 128 + srow) * (long)K + scol;
  const u16* gb = BT + (bn * 128 + srow) * (long)K + scol;
  char* lA = (char*)sA + wave * 1024;
  char* lB = (char*)sB + wave * 1024;

  f4 acc[4][4];
#pragma unroll
  for (int i = 0; i < 4; ++i)
#pragma unroll
    for (int j = 0; j < 4; ++j) acc[i][j] = f4{0.f, 0.f, 0.f, 0.f};

  for (int k0 = 0; k0 < K; k0 += 32) {
    if (k0) __syncthreads();
    GLD_LDS16(ga + k0, lA);
    GLD_LDS16(ga + 64 * (long)K + k0, lA + 4096);
    GLD_LDS16(gb + k0, lB);
    GLD_LDS16(gb + 64 * (long)K + k0, lB + 4096);
    __syncthreads();
    s8v aF[4], bF[4];
#pragma unroll
    for (int i = 0; i < 4; ++i)
      aF[i] = *(const s8v*)(sA + (wm * 64 + i * 16 + l16) * 32 + quad * 8);
#pragma unroll
    for (int j = 0; j < 4; ++j)
      bF[j] = *(const s8v*)(sB + (wn * 64 + j * 16 + l16) * 32 + quad * 8);
#pragma unroll
    for (int i = 0; i < 4; ++i)
#pragma unroll
      for (int j = 0; j < 4; ++j)
        acc[i][j] = __builtin_amdgcn_mfma_f32_16x16x32_bf16(aF[i], bF[j], acc[i][j], 0, 0, 0);
  }

#pragma unroll
  for (int i = 0; i < 4; ++i) {
#pragma unroll
    for (int j = 0; j < 4; ++j) {
      long row = bm * 128 + wm * 64 + i * 16 + quad * 4;
      int col = (int)bn * 128 + wn * 64 + j * 16 + l16;
      float bcol = bias[col];
#pragma unroll
      for (int r = 0; r < 4; ++r) {
        float val = acc[i][j][r] + bcol;
        if (EPI == 1) {
          ((u16*)outp)[(row + r) * (long)N + col] = f2b(val > 0.f ? val : 0.f);
        } else {
          ((float*)outp)[(row + r) * (long)N + col] = resid[(row + r) * (long)N + col] + val;
        }
      }
    }
  }
}

extern "C" void kernel_launch(void* const* d_in, const int* in_sizes, int n_in, void* d_out,
                              int out_size, void* d_ws, size_t ws_size, hipStream_t stream) {
  const float* x = (const float*)d_in[0];
  const float* Wq = (const float*)d_in[1];
  const float* Wk = (const float*)d_in[2];
  const float* Wv = (const float*)d_in[3];
  const float* Wo = (const float*)d_in[4];
  const float* bo = (const float*)d_in[5];
  const float* W1 = (const float*)d_in[6];
  const float* b1 = (const float*)d_in[7];
  const float* W2 = (const float*)d_in[8];
  const float* b2 = (const float*)d_in[9];
  const float* g1 = (const float*)d_in[10];
  const float* be1 = (const float*)d_in[11];
  const float* g2 = (const float*)d_in[12];
  const float* be2 = (const float*)d_in[13];

  char* ws = (char*)d_ws;
  const size_t MB = 1ull << 20;
  u16* nx = (u16*)(ws + 0);            // 16 MB  LN1 out; reused as attn out
  u16* qb = (u16*)(ws + 16 * MB);      // 16 MB  q; reused as nx2
  u16* kb = (u16*)(ws + 32 * MB);      // 16 MB
  u16* vb = (u16*)(ws + 48 * MB);      // 16 MB
  float* x1 = (float*)(ws + 64 * MB);  // 32 MB  attn-sublayer output (fp32 residual)
  u16* h1 = (u16*)(ws + 96 * MB);      // 64 MB  MLP hidden
  u16* WoT = (u16*)(ws + 160 * MB);    // 2 MB
  u16* W1T = (u16*)(ws + 162 * MB);    // 8 MB
  u16* W2T = (u16*)(ws + 170 * MB);    // 8 MB
  u16* WqT = (u16*)(ws + 178 * MB);
  u16* WkT = WqT + 64 * 64;
  u16* WvT = WkT + 64 * 64;
  u16* ob = nx;
  u16* nx2 = qb;

  k_transpose<<<dim3(32, 32), 256, 0, stream>>>(Wo, WoT, 1024, 1024);
  k_transpose<<<dim3(128, 32), 256, 0, stream>>>(W1, W1T, 1024, 4096);
  k_transpose<<<dim3(32, 128), 256, 0, stream>>>(W2, W2T, 4096, 1024);
  k_transpose<<<dim3(2, 2), 256, 0, stream>>>(Wq, WqT, 64, 64);
  k_transpose<<<dim3(2, 2), 256, 0, stream>>>(Wk, WkT, 64, 64);
  k_transpose<<<dim3(2, 2), 256, 0, stream>>>(Wv, WvT, 64, 64);

  k_layernorm<<<8192, 256, 0, stream>>>(x, g1, be1, nx);
  k_qkv<<<2048, 256, 0, stream>>>(nx, WqT, WkT, WvT, qb, kb, vb);
  k_attn_mfma<<<dim3(128, 16), 256, 0, stream>>>(qb, kb, vb, ob);
  k_gemm_bt<2><<<dim3(64, 8), 256, 0, stream>>>(ob, WoT, bo, x, x1, 8192, 1024, 1024);

  k_layernorm<<<8192, 256, 0, stream>>>(x1, g2, be2, nx2);
  k_gemm_bt<1><<<dim3(64, 32), 256, 0, stream>>>(nx2, W1T, b1, nullptr, h1, 8192, 4096, 1024);
  k_gemm_bt<2><<<dim3(64, 8), 256, 0, stream>>>(h1, W2T, b2, x1, d_out, 8192, 1024, 4096);
}

// Round 3
// 457.198 us; speedup vs baseline: 3.1627x; 1.0709x over previous
//
#include <hip/hip_runtime.h>

typedef unsigned short u16;
typedef __attribute__((ext_vector_type(4))) float f4;
typedef __attribute__((ext_vector_type(8))) short s8v;    // 8 x bf16 MFMA frag (4 VGPRs)
typedef __attribute__((ext_vector_type(4))) unsigned short u16x4;

#define DEVINL __device__ __forceinline__

DEVINL float b2f(u16 u) { union { unsigned i; float f; } x; x.i = ((unsigned)u) << 16; return x.f; }
DEVINL u16 f2b(float f) {
  union { float f; unsigned i; } x; x.f = f;
  unsigned r = 0x7FFFu + ((x.i >> 16) & 1u);
  return (u16)((x.i + r) >> 16);
}

#define GLD_LDS16(g, l)                                                        \
  __builtin_amdgcn_global_load_lds((__attribute__((address_space(1))) void*)(g), \
                                   (__attribute__((address_space(3))) void*)(l), 16, 0, 0)

// ---------------- transpose + fp32->bf16 cast: out[C,R] = cast(in[R,C]^T) ----------------
__global__ __launch_bounds__(256) void k_transpose(const float* __restrict__ in,
                                                   u16* __restrict__ out, int R, int C) {
  __shared__ float t[32][33];
  int tx = threadIdx.x & 31, ty = threadIdx.x >> 5;
  int c0 = blockIdx.x * 32, r0 = blockIdx.y * 32;
#pragma unroll
  for (int i = 0; i < 32; i += 8)
    t[ty + i][tx] = in[(long)(r0 + ty + i) * C + (c0 + tx)];
  __syncthreads();
#pragma unroll
  for (int i = 0; i < 32; i += 8)
    out[(long)(c0 + ty + i) * R + (r0 + tx)] = f2b(t[tx][ty + i]);
}

// ---------------- bf16 V transpose: v [B,S,H,D] -> vt [B,H,D,S] ----------------
__global__ __launch_bounds__(256) void k_vtrans(const u16* __restrict__ v, u16* __restrict__ vt) {
  __shared__ u16 t[64][72];
  int bh = blockIdx.x, b = bh >> 4, h = bh & 15;
  int s0 = blockIdx.y * 64;
  int tid = threadIdx.x;
#pragma unroll
  for (int p = 0; p < 2; ++p) {
    int idx = p * 256 + tid;
    int sl = idx >> 3, c8 = (idx & 7) * 8;
    *(s8v*)(&t[sl][c8]) = *(const s8v*)(v + (((long)(b * 1024 + s0 + sl) * 16 + h) * 64) + c8);
  }
  __syncthreads();
#pragma unroll
  for (int p = 0; p < 2; ++p) {
    int idx = p * 256 + tid;
    int d = idx >> 3, c8 = (idx & 7) * 8;
    s8v o;
#pragma unroll
    for (int e = 0; e < 8; ++e) o[e] = (short)t[c8 + e][d];
    *(s8v*)(vt + ((long)bh * 64 + d) * 1024 + s0 + c8) = o;
  }
}

// ---------------- LayerNorm over E=1024, one row per block, bf16 out ----------------
__global__ __launch_bounds__(256) void k_layernorm(const float* __restrict__ x,
                                                   const float* __restrict__ g,
                                                   const float* __restrict__ be,
                                                   u16* __restrict__ out) {
  long row = blockIdx.x;
  int tid = threadIdx.x;
  f4 v = ((const f4*)(x + row * 1024))[tid];
  float s = v[0] + v[1] + v[2] + v[3];
  float s2 = v[0] * v[0] + v[1] * v[1] + v[2] * v[2] + v[3] * v[3];
#pragma unroll
  for (int off = 32; off > 0; off >>= 1) {
    s += __shfl_down(s, off, 64);
    s2 += __shfl_down(s2, off, 64);
  }
  __shared__ float red[8];
  int wv = tid >> 6, ln = tid & 63;
  if (ln == 0) { red[wv] = s; red[4 + wv] = s2; }
  __syncthreads();
  s = red[0] + red[1] + red[2] + red[3];
  s2 = red[4] + red[5] + red[6] + red[7];
  float mean = s * (1.0f / 1024.0f);
  float var = s2 * (1.0f / 1024.0f) - mean * mean;
  float rs = rsqrtf(var + 1e-5f);
  f4 gg = ((const f4*)g)[tid];
  f4 bb = ((const f4*)be)[tid];
  u16x4 o;
#pragma unroll
  for (int i = 0; i < 4; ++i) o[i] = f2b((v[i] - mean) * rs * gg[i] + bb[i]);
  ((u16x4*)(out + row * 1024))[tid] = o;
}

// ---------------- QKV: [131072,64] @ [64,64] x3, MFMA 16x16x32 bf16 ----------------
__global__ __launch_bounds__(256) void k_qkv(const u16* __restrict__ nx, const u16* __restrict__ WqT,
                                             const u16* __restrict__ WkT, const u16* __restrict__ WvT,
                                             u16* __restrict__ q, u16* __restrict__ k,
                                             u16* __restrict__ v) {
  int tid = threadIdx.x, lane = tid & 63, wave = tid >> 6;
  int quad = lane >> 4, l16 = lane & 15;
  long rbase = (long)blockIdx.x * 64 + wave * 16;
  s8v a0 = *(const s8v*)(nx + (rbase + l16) * 64 + quad * 8);
  s8v a1 = *(const s8v*)(nx + (rbase + l16) * 64 + 32 + quad * 8);
  const u16* Ws[3] = {WqT, WkT, WvT};
  u16* Os[3] = {q, k, v};
#pragma unroll
  for (int t = 0; t < 3; ++t) {
#pragma unroll
    for (int j = 0; j < 4; ++j) {
      s8v b0 = *(const s8v*)(Ws[t] + (j * 16 + l16) * 64 + quad * 8);
      s8v b1 = *(const s8v*)(Ws[t] + (j * 16 + l16) * 64 + 32 + quad * 8);
      f4 acc = {0.f, 0.f, 0.f, 0.f};
      acc = __builtin_amdgcn_mfma_f32_16x16x32_bf16(a0, b0, acc, 0, 0, 0);
      acc = __builtin_amdgcn_mfma_f32_16x16x32_bf16(a1, b1, acc, 0, 0, 0);
#pragma unroll
      for (int r = 0; r < 4; ++r)
        Os[t][(rbase + quad * 4 + r) * 64 + j * 16 + l16] = f2b(acc[r]);
    }
  }
}

// ---------------- MFMA flash attention (causal) ----------------
// q,k: [B,S,H,D] bf16; vt: [B,H,D,S] bf16 (pre-transposed). o: [B,S,H,D].
__global__ __launch_bounds__(256) void k_attn_mfma(const u16* __restrict__ q,
                                                   const u16* __restrict__ kk,
                                                   const u16* __restrict__ vt,
                                                   u16* __restrict__ o) {
  constexpr int LDK = 72;  // row stride (u16): 144 B -> b128-aligned rows, non-pow2 banks
  __shared__ u16 Ks[64 * LDK];      // [key][d]
  __shared__ u16 Vt[64 * LDK];      // [d][key]
  __shared__ u16 Ps[4][16 * LDK];   // per-wave P [qrow][key]
  int tid = threadIdx.x, lane = tid & 63, wave = tid >> 6;
  int quad = lane >> 4, l16 = lane & 15;
  int b = blockIdx.x >> 4, h = blockIdx.x & 15;
  int qi = (int)gridDim.y - 1 - (int)blockIdx.y;  // heavy q-tiles dispatch first
  int q0 = qi * 64 + wave * 16;

  const u16* qp = q + (((long)(b * 1024 + q0 + l16)) * 16 + h) * 64;
  s8v aq0 = *(const s8v*)(qp + quad * 8);
  s8v aq1 = *(const s8v*)(qp + 32 + quad * 8);

  f4 O[4];
  float m_[4], l_[4];
#pragma unroll
  for (int jd = 0; jd < 4; ++jd) O[jd] = f4{0.f, 0.f, 0.f, 0.f};
#pragma unroll
  for (int r = 0; r < 4; ++r) { m_[r] = -__builtin_inff(); l_[r] = 0.f; }

  for (int kt = 0; kt <= qi; ++kt) {
    __syncthreads();  // protect Ks/Vt reuse across tiles
    // ---- stage K [key][d] and V^T [d][key], both b128 ----
#pragma unroll
    for (int p = 0; p < 2; ++p) {
      int idx = p * 256 + tid;
      int row = idx >> 3, c8 = (idx & 7) * 8;
      *(s8v*)(Ks + row * LDK + c8) =
          *(const s8v*)(kk + (((long)(b * 1024 + kt * 64 + row)) * 16 + h) * 64 + c8);
      *(s8v*)(Vt + row * LDK + c8) =
          *(const s8v*)(vt + ((long)blockIdx.x * 64 + row) * 1024 + kt * 64 + c8);
    }
    __syncthreads();

    // ---- S = Q K^T ----
    f4 sf[4];
#pragma unroll
    for (int jn = 0; jn < 4; ++jn) {
      s8v b0 = *(const s8v*)(Ks + (jn * 16 + l16) * LDK + quad * 8);
      s8v b1 = *(const s8v*)(Ks + (jn * 16 + l16) * LDK + 32 + quad * 8);
      f4 acc = f4{0.f, 0.f, 0.f, 0.f};
      acc = __builtin_amdgcn_mfma_f32_16x16x32_bf16(aq0, b0, acc, 0, 0, 0);
      acc = __builtin_amdgcn_mfma_f32_16x16x32_bf16(aq1, b1, acc, 0, 0, 0);
      sf[jn] = acc;
    }
    // ---- scale + causal mask + row max ----
    bool diag = (kt == qi);
    float rm[4];
#pragma unroll
    for (int r = 0; r < 4; ++r) rm[r] = -__builtin_inff();
#pragma unroll
    for (int jn = 0; jn < 4; ++jn)
#pragma unroll
      for (int r = 0; r < 4; ++r) {
        float v = sf[jn][r] * 0.03125f;
        if (diag && (jn * 16 + l16 > wave * 16 + quad * 4 + r)) v = -__builtin_inff();
        sf[jn][r] = v;
        rm[r] = fmaxf(rm[r], v);
      }
#pragma unroll
    for (int off = 1; off < 16; off <<= 1)
#pragma unroll
      for (int r = 0; r < 4; ++r) rm[r] = fmaxf(rm[r], __shfl_xor(rm[r], off, 64));
    // ---- online-softmax update ----
    float alpha[4], rs[4];
#pragma unroll
    for (int r = 0; r < 4; ++r) {
      float mn = fmaxf(m_[r], rm[r]);
      alpha[r] = __expf(m_[r] - mn);
      m_[r] = mn;
      rs[r] = 0.f;
    }
#pragma unroll
    for (int jn = 0; jn < 4; ++jn)
#pragma unroll
      for (int r = 0; r < 4; ++r) {
        float p = __expf(sf[jn][r] - m_[r]);
        rs[r] += p;
        Ps[wave][(quad * 4 + r) * LDK + jn * 16 + l16] = f2b(p);
      }
#pragma unroll
    for (int off = 1; off < 16; off <<= 1)
#pragma unroll
      for (int r = 0; r < 4; ++r) rs[r] += __shfl_xor(rs[r], off, 64);
#pragma unroll
    for (int r = 0; r < 4; ++r) l_[r] = l_[r] * alpha[r] + rs[r];
#pragma unroll
    for (int jd = 0; jd < 4; ++jd)
#pragma unroll
      for (int r = 0; r < 4; ++r) O[jd][r] *= alpha[r];
    // wave-local RAW on Ps (per-wave buffer): drain DS queue, no barrier needed
    asm volatile("s_waitcnt lgkmcnt(0)" ::: "memory");
    // ---- O += P V ----
    s8v p0 = *(const s8v*)(&Ps[wave][l16 * LDK + quad * 8]);
    s8v p1 = *(const s8v*)(&Ps[wave][l16 * LDK + 32 + quad * 8]);
#pragma unroll
    for (int jd = 0; jd < 4; ++jd) {
      s8v b0 = *(const s8v*)(Vt + (jd * 16 + l16) * LDK + quad * 8);
      s8v b1 = *(const s8v*)(Vt + (jd * 16 + l16) * LDK + 32 + quad * 8);
      O[jd] = __builtin_amdgcn_mfma_f32_16x16x32_bf16(p0, b0, O[jd], 0, 0, 0);
      O[jd] = __builtin_amdgcn_mfma_f32_16x16x32_bf16(p1, b1, O[jd], 0, 0, 0);
    }
  }
  // ---- epilogue ----
#pragma unroll
  for (int r = 0; r < 4; ++r) {
    float inv = 1.0f / l_[r];
    u16* op = o + (((long)(b * 1024 + q0 + quad * 4 + r)) * 16 + h) * 64;
#pragma unroll
    for (int jd = 0; jd < 4; ++jd) op[jd * 16 + l16] = f2b(O[jd][r] * inv);
  }
}

// ---------------- 128x128 GEMM, double-buffered LDS staging ----------------
// A[M,K] bf16, BT[N,K] bf16, fp32 acc.
// EPI=1: out = bf16(relu(acc+bias));  EPI=2: out = fp32(resid + acc + bias)
// Pipeline: GLDs for tile k+1 issued right after the barrier, so the
// vmcnt(0)-drain at the NEXT barrier waits on loads that had a full compute
// phase in flight (vs zero overlap in the single-buffer m97 form). Matters
// most for the 512-block (2 blocks/CU) dispatches where no other resident
// block hides the latency.
template <int EPI>
__global__ __launch_bounds__(256) void k_gemm_bt(const u16* __restrict__ A, const u16* __restrict__ BT,
                                                 const float* __restrict__ bias,
                                                 const float* __restrict__ resid,
                                                 void* __restrict__ outp, int M, int N, int K) {
  __shared__ u16 sA[2][128 * 32];  // unpadded: global_load_lds needs lane-linear dest
  __shared__ u16 sB[2][128 * 32];
  int tid = threadIdx.x, lane = tid & 63, wave = tid >> 6;
  int quad = lane >> 4, l16 = lane & 15;
  int wm = wave >> 1, wn = wave & 1;
  long bm = blockIdx.x, bn = blockIdx.y;
  int srow = tid >> 2, scol = (tid & 3) * 8;
  const u16* ga = A + (bm * 128 + srow) * (long)K + scol;
  const u16* gb = BT + (bn * 128 + srow) * (long)K + scol;
  int woff = wave * 1024;  // bytes; wave-uniform LDS base (64 lanes x 16 B)

  f4 acc[4][4];
#pragma unroll
  for (int i = 0; i < 4; ++i)
#pragma unroll
    for (int j = 0; j < 4; ++j) acc[i][j] = f4{0.f, 0.f, 0.f, 0.f};

  {  // prologue: stage tile 0 into buf 0
    char* lA = (char*)&sA[0][0] + woff;
    char* lB = (char*)&sB[0][0] + woff;
    GLD_LDS16(ga, lA);
    GLD_LDS16(ga + 64 * (long)K, lA + 4096);
    GLD_LDS16(gb, lB);
    GLD_LDS16(gb + 64 * (long)K, lB + 4096);
  }

  for (int k0 = 0; k0 < K; k0 += 32) {
    int cur = (k0 >> 5) & 1;
    __syncthreads();  // drains this wave's GLDs for buf[cur] (in flight since last iter)
    int k1 = k0 + 32;
    if (k1 < K) {  // prefetch next tile into the other buffer
      char* lA = (char*)&sA[cur ^ 1][0] + woff;
      char* lB = (char*)&sB[cur ^ 1][0] + woff;
      GLD_LDS16(ga + k1, lA);
      GLD_LDS16(ga + 64 * (long)K + k1, lA + 4096);
      GLD_LDS16(gb + k1, lB);
      GLD_LDS16(gb + 64 * (long)K + k1, lB + 4096);
    }
    const u16* cA = sA[cur];
    const u16* cB = sB[cur];
    s8v aF[4], bF[4];
#pragma unroll
    for (int i = 0; i < 4; ++i)
      aF[i] = *(const s8v*)(cA + (wm * 64 + i * 16 + l16) * 32 + quad * 8);
#pragma unroll
    for (int j = 0; j < 4; ++j)
      bF[j] = *(const s8v*)(cB + (wn * 64 + j * 16 + l16) * 32 + quad * 8);
#pragma unroll
    for (int i = 0; i < 4; ++i)
#pragma unroll
      for (int j = 0; j < 4; ++j)
        acc[i][j] = __builtin_amdgcn_mfma_f32_16x16x32_bf16(aF[i], bF[j], acc[i][j], 0, 0, 0);
  }

#pragma unroll
  for (int i = 0; i < 4; ++i) {
#pragma unroll
    for (int j = 0; j < 4; ++j) {
      long row = bm * 128 + wm * 64 + i * 16 + quad * 4;
      int col = (int)bn * 128 + wn * 64 + j * 16 + l16;
      float bcol = bias[col];
#pragma unroll
      for (int r = 0; r < 4; ++r) {
        float val = acc[i][j][r] + bcol;
        if (EPI == 1) {
          ((u16*)outp)[(row + r) * (long)N + col] = f2b(val > 0.f ? val : 0.f);
        } else {
          ((float*)outp)[(row + r) * (long)N + col] = resid[(row + r) * (long)N + col] + val;
        }
      }
    }
  }
}

extern "C" void kernel_launch(void* const* d_in, const int* in_sizes, int n_in, void* d_out,
                              int out_size, void* d_ws, size_t ws_size, hipStream_t stream) {
  const float* x = (const float*)d_in[0];
  const float* Wq = (const float*)d_in[1];
  const float* Wk = (const float*)d_in[2];
  const float* Wv = (const float*)d_in[3];
  const float* Wo = (const float*)d_in[4];
  const float* bo = (const float*)d_in[5];
  const float* W1 = (const float*)d_in[6];
  const float* b1 = (const float*)d_in[7];
  const float* W2 = (const float*)d_in[8];
  const float* b2 = (const float*)d_in[9];
  const float* g1 = (const float*)d_in[10];
  const float* be1 = (const float*)d_in[11];
  const float* g2 = (const float*)d_in[12];
  const float* be2 = (const float*)d_in[13];

  char* ws = (char*)d_ws;
  const size_t MB = 1ull << 20;
  u16* nx = (u16*)(ws + 0);            // 16 MB  LN1 out; reused as attn out
  u16* qb = (u16*)(ws + 16 * MB);      // 16 MB  q; reused as nx2
  u16* kb = (u16*)(ws + 32 * MB);      // 16 MB
  u16* vb = (u16*)(ws + 48 * MB);      // 16 MB
  float* x1 = (float*)(ws + 64 * MB);  // 32 MB  attn-sublayer output (fp32 residual)
  u16* h1 = (u16*)(ws + 96 * MB);      // 64 MB  MLP hidden (after attn)
  u16* vtr = (u16*)(ws + 96 * MB);     // 16 MB  V^T [B,H,D,S]; dead before h1 is written
  u16* WoT = (u16*)(ws + 160 * MB);    // 2 MB
  u16* W1T = (u16*)(ws + 162 * MB);    // 8 MB
  u16* W2T = (u16*)(ws + 170 * MB);    // 8 MB
  u16* WqT = (u16*)(ws + 178 * MB);
  u16* WkT = WqT + 64 * 64;
  u16* WvT = WkT + 64 * 64;
  u16* ob = nx;
  u16* nx2 = qb;

  k_transpose<<<dim3(32, 32), 256, 0, stream>>>(Wo, WoT, 1024, 1024);
  k_transpose<<<dim3(128, 32), 256, 0, stream>>>(W1, W1T, 1024, 4096);
  k_transpose<<<dim3(32, 128), 256, 0, stream>>>(W2, W2T, 4096, 1024);
  k_transpose<<<dim3(2, 2), 256, 0, stream>>>(Wq, WqT, 64, 64);
  k_transpose<<<dim3(2, 2), 256, 0, stream>>>(Wk, WkT, 64, 64);
  k_transpose<<<dim3(2, 2), 256, 0, stream>>>(Wv, WvT, 64, 64);

  k_layernorm<<<8192, 256, 0, stream>>>(x, g1, be1, nx);
  k_qkv<<<2048, 256, 0, stream>>>(nx, WqT, WkT, WvT, qb, kb, vb);
  k_vtrans<<<dim3(128, 16), 256, 0, stream>>>(vb, vtr);
  k_attn_mfma<<<dim3(128, 16), 256, 0, stream>>>(qb, kb, vtr, ob);
  k_gemm_bt<2><<<dim3(64, 8), 256, 0, stream>>>(ob, WoT, bo, x, x1, 8192, 1024, 1024);

  k_layernorm<<<8192, 256, 0, stream>>>(x1, g2, be2, nx2);
  k_gemm_bt<1><<<dim3(64, 32), 256, 0, stream>>>(nx2, W1T, b1, nullptr, h1, 8192, 4096, 1024);
  k_gemm_bt<2><<<dim3(64, 8), 256, 0, stream>>>(h1, W2T, b2, x1, d_out, 8192, 1024, 4096);
}